// Round 2
// baseline (119.437 us; speedup 1.0000x reference)
//
#include <hip/hip_runtime.h>
#include <hip/hip_bf16.h>
#include <float.h>

// Problem constants (fixed by setup_inputs)
constexpr int B = 8, N = 4096, M = 4096, E = 12288;
constexpr int BLOCK = 256;
constexpr int CH = 512;                       // ref points per LDS chunk
constexpr int NCH = M / CH;                   // 8 chunks
constexpr int CHAM_BLOCKS = 2 * B * (N / BLOCK);  // 256 (2 dirs x 8 b x 16 tiles)
constexpr int EDGE_BLOCKS = (B * E) / BLOCK;      // 384
constexpr int EPB = (E / BLOCK);                  // 48 edge blocks per batch

// ws layout (floats):
//   [0 .. 256)        chamfer per-block partial sqrt-sums
//   [256 .. 256+768)  edge per-block (sumL, sumL2) pairs
// Every slot is written unconditionally -> no init kernel needed despite 0xAA poison.

__global__ __launch_bounds__(BLOCK) void fused_kernel(
    const float* __restrict__ pred, const float* __restrict__ gt,
    const int* __restrict__ edges, float* __restrict__ ws) {
    const int bid = blockIdx.x;
    const int t = threadIdx.x;

    if (bid < CHAM_BLOCKS) {
        // ---------------- chamfer full-sweep block ----------------
        const int dir = bid >> 7;          // 0: q=pred/ref=gt, 1: swapped
        const int b   = (bid >> 4) & 7;
        const int qt  = bid & 15;
        const float* __restrict__ q   = dir ? gt   : pred;
        const float* __restrict__ ref = dir ? pred : gt;

        // this thread's single query point
        const float* qp = q + ((size_t)b * N + qt * BLOCK + t) * 3;
        const float qx = qp[0], qy = qp[1], qz = qp[2];
        const float h1 = 0.5f * (qx * qx + qy * qy + qz * qz);

        __shared__ float4 tile[2][CH];     // double-buffered ref chunks
        const float2* rbase = (const float2*)(ref + (size_t)b * M * 3);

        // stage chunk 0: thread t loads ref points 2t, 2t+1 (3 coalesced float2)
        float2 r0 = rbase[3 * t], r1 = rbase[3 * t + 1], r2 = rbase[3 * t + 2];
        {
            const float x0 = r0.x, y0 = r0.y, z0 = r1.x;
            const float x1 = r1.y, y1 = r2.x, z1 = r2.y;
            tile[0][2 * t]     = make_float4(x0, y0, z0, 0.5f * (x0*x0 + y0*y0 + z0*z0));
            tile[0][2 * t + 1] = make_float4(x1, y1, z1, 0.5f * (x1*x1 + y1*y1 + z1*z1));
        }
        __syncthreads();

        float acc[8];
#pragma unroll
        for (int i = 0; i < 8; i++) acc[i] = FLT_MAX;

        auto compute8 = [&](const float4* pp) {
#pragma unroll
            for (int i = 0; i < 8; ++i) {
                const float4 p = pp[i];
                float d = h1 + p.w;                 // 0.5|q|^2 + 0.5|p|^2
                d = fmaf(-qx, p.x, d);
                d = fmaf(-qy, p.y, d);
                d = fmaf(-qz, p.z, d);              // ... - q.p  == 0.5 d^2
                acc[i] = fminf(acc[i], d);
            }
        };
        auto load8 = [&](float4* dst, const float4* tl, int g) {
#pragma unroll
            for (int i = 0; i < 8; ++i) dst[i] = tl[g * 8 + i];
        };

        for (int c = 0; c < NCH; ++c) {
            // T14: issue next chunk's global loads early; LDS-write after compute
            if (c + 1 < NCH) {
                const float2* nb = rbase + (size_t)(c + 1) * (CH * 3 / 2);
                r0 = nb[3 * t]; r1 = nb[3 * t + 1]; r2 = nb[3 * t + 2];
            }

            const float4* tl = tile[c & 1];
            float4 bufA[8], bufB[8];
            load8(bufA, tl, 0);
#pragma unroll 1
            for (int g = 0; g < CH / 8 - 2; g += 2) {   // g = 0..60
                load8(bufB, tl, g + 1);
                compute8(bufA);
                load8(bufA, tl, g + 2);
                compute8(bufB);
            }
            load8(bufB, tl, CH / 8 - 1);                // group 63
            compute8(bufA);                              // group 62
            compute8(bufB);                              // group 63

            if (c + 1 < NCH) {
                const int nb = (c + 1) & 1;
                const float x0 = r0.x, y0 = r0.y, z0 = r1.x;
                const float x1 = r1.y, y1 = r2.x, z1 = r2.y;
                tile[nb][2 * t]     = make_float4(x0, y0, z0, 0.5f * (x0*x0 + y0*y0 + z0*z0));
                tile[nb][2 * t + 1] = make_float4(x1, y1, z1, 0.5f * (x1*x1 + y1*y1 + z1*z1));
            }
            __syncthreads();
        }

        // epilogue: final min -> distance -> block sum -> one store
        float m = acc[0];
#pragma unroll
        for (int i = 1; i < 8; i++) m = fminf(m, acc[i]);
        float s = sqrtf(fmaxf(2.0f * m, 0.0f));
#pragma unroll
        for (int o = 32; o > 0; o >>= 1) s += __shfl_down(s, o, 64);
        __shared__ float wsum[4];
        const int wave = t >> 6, lane = t & 63;
        if (lane == 0) wsum[wave] = s;
        __syncthreads();
        if (t == 0) {
            ws[bid] = wsum[0] + wsum[1] + wsum[2] + wsum[3];
        }
    } else {
        // ---------------- edge-length block ----------------
        const int eb = bid - CHAM_BLOCKS;           // 0..383
        const int b  = eb / EPB;
        const int e  = (eb - b * EPB) * BLOCK + t;  // < E always (384*256 == B*E)
        const int i0 = edges[2 * e], i1 = edges[2 * e + 1];
        const float* p0 = pred + ((size_t)b * N + i0) * 3;
        const float* p1 = pred + ((size_t)b * N + i1) * 3;
        const float dx = p0[0] - p1[0];
        const float dy = p0[1] - p1[1];
        const float dz = p0[2] - p1[2];
        float L  = sqrtf(dx * dx + dy * dy + dz * dz);
        float L2 = L * L;
#pragma unroll
        for (int o = 32; o > 0; o >>= 1) {
            L  += __shfl_down(L, o, 64);
            L2 += __shfl_down(L2, o, 64);
        }
        __shared__ float w1[4], w2[4];
        const int wave = t >> 6, lane = t & 63;
        if (lane == 0) { w1[wave] = L; w2[wave] = L2; }
        __syncthreads();
        if (t == 0) {
            ws[CHAM_BLOCKS + 2 * eb]     = w1[0] + w1[1] + w1[2] + w1[3];
            ws[CHAM_BLOCKS + 2 * eb + 1] = w2[0] + w2[1] + w2[2] + w2[3];
        }
    }
}

__global__ __launch_bounds__(256) void final_kernel(
    const float* __restrict__ ws, float* __restrict__ out) {
    const int t = threadIdx.x;
    float sc = ws[t];                                   // 256 chamfer partials
    float s1 = ws[CHAM_BLOCKS + 2 * t];
    float s2 = ws[CHAM_BLOCKS + 2 * t + 1];
    if (t < EDGE_BLOCKS - 256) {                        // pairs 256..383
        s1 += ws[CHAM_BLOCKS + 2 * (t + 256)];
        s2 += ws[CHAM_BLOCKS + 2 * (t + 256) + 1];
    }
#pragma unroll
    for (int o = 32; o > 0; o >>= 1) {
        sc += __shfl_down(sc, o, 64);
        s1 += __shfl_down(s1, o, 64);
        s2 += __shfl_down(s2, o, 64);
    }
    __shared__ float w[3][4];
    const int wave = t >> 6, lane = t & 63;
    if (lane == 0) { w[0][wave] = sc; w[1][wave] = s1; w[2][wave] = s2; }
    __syncthreads();
    if (t == 0) {
        float S = 0.0f, A = 0.0f, C = 0.0f;
#pragma unroll
        for (int i = 0; i < 4; i++) { S += w[0][i]; A += w[1][i]; C += w[2][i]; }
        const float K = (float)(B * E);                 // 98304
        const float var = (C - A * A / K) / (K - 1.0f);
        out[0] = S / 32768.0f + 0.1f * var;             // cd + 0.1 * edge_var
    }
}

extern "C" void kernel_launch(void* const* d_in, const int* in_sizes, int n_in,
                              void* d_out, int out_size, void* d_ws, size_t ws_size,
                              hipStream_t stream) {
    const float* pred  = (const float*)d_in[0];
    const float* gt    = (const float*)d_in[1];
    const int*   edges = (const int*)d_in[2];
    float* out = (float*)d_out;
    float* wsf = (float*)d_ws;

    fused_kernel<<<CHAM_BLOCKS + EDGE_BLOCKS, BLOCK, 0, stream>>>(pred, gt, edges, wsf);
    final_kernel<<<1, 256, 0, stream>>>(wsf, out);
}

// Round 3
// 95.197 us; speedup vs baseline: 1.2546x; 1.2546x over previous
//
#include <hip/hip_runtime.h>
#include <hip/hip_bf16.h>
#include <float.h>

// Problem constants (fixed by setup_inputs)
constexpr int B = 8, N = 4096, M = 4096, E = 12288;
constexpr int BLOCK = 256;
constexpr int VEC = 4;                        // register queries per thread
constexpr int QPB = BLOCK * VEC;              // 1024 queries per block
constexpr int QT = N / QPB;                   // 4 query tiles
constexpr int SEG = 8;                        // ref-sweep split
constexpr int RPS = M / SEG;                  // 512 refs per segment
constexpr int CHAM_BLOCKS = 2 * B * QT * SEG; // 512
constexpr int EDGE_BLOCKS = (B * E) / BLOCK;  // 384
constexpr int EPB = E / BLOCK;                // 48 edge blocks per batch

// ws layout:
//   uint  [0 .. 65536)            per-query min(0.5*d^2) as float-bits (atomicMin)
//         -- harness poison 0xAAAAAAAA > any positive-float bits, acts as +inf: no init!
//   float [65536 .. 65536+768)    edge per-block (sumL, sumL2) pairs

__global__ __launch_bounds__(BLOCK) void fused_kernel(
    const float* __restrict__ pred, const float* __restrict__ gt,
    const int* __restrict__ edges, unsigned* __restrict__ ws) {
    const int bid = blockIdx.x;
    const int t = threadIdx.x;

    if (bid < CHAM_BLOCKS) {
        // ---------------- chamfer partial-sweep block ----------------
        const int dir = bid >> 8;            // 0: q=pred/ref=gt, 1: swapped
        const int r   = bid & 255;
        const int b   = r >> 5;
        const int rem = r & 31;
        const int qt  = rem >> 3;            // 0..3
        const int sg  = rem & 7;             // 0..7
        const float* __restrict__ q   = dir ? gt   : pred;
        const float* __restrict__ ref = dir ? pred : gt;
        unsigned* __restrict__ minOut = ws + dir * (B * N) + b * N + qt * QPB;

        // this thread's VEC query points (coalesced-ish scalar loads, tiny cost)
        float qx[VEC], qy[VEC], qz[VEC], h1[VEC];
#pragma unroll
        for (int i = 0; i < VEC; i++) {
            const int n = qt * QPB + i * BLOCK + t;
            const float* p = q + ((size_t)b * N + n) * 3;
            qx[i] = p[0]; qy[i] = p[1]; qz[i] = p[2];
            h1[i] = 0.5f * (qx[i] * qx[i] + qy[i] * qy[i] + qz[i] * qz[i]);
        }

        // stage this segment's 512 ref points into LDS: {x,y,z, 0.5*|p|^2}
        __shared__ float4 tile[RPS];
        {
            const float2* rb = (const float2*)(ref + ((size_t)b * M + sg * RPS) * 3);
            const float2 r0 = rb[3 * t], r1 = rb[3 * t + 1], r2 = rb[3 * t + 2];
            const float x0 = r0.x, y0 = r0.y, z0 = r1.x;
            const float x1 = r1.y, y1 = r2.x, z1 = r2.y;
            tile[2 * t]     = make_float4(x0, y0, z0, 0.5f * (x0*x0 + y0*y0 + z0*z0));
            tile[2 * t + 1] = make_float4(x1, y1, z1, 0.5f * (x1*x1 + y1*y1 + z1*z1));
        }
        __syncthreads();

        float mn[VEC];
#pragma unroll
        for (int i = 0; i < VEC; i++) mn[i] = FLT_MAX;

#pragma unroll 8
        for (int m = 0; m < RPS; ++m) {
            const float4 p = tile[m];        // broadcast read: conflict-free
#pragma unroll
            for (int i = 0; i < VEC; ++i) {
                float d = h1[i] + p.w;       // 0.5|q|^2 + 0.5|p|^2
                d = fmaf(-qx[i], p.x, d);
                d = fmaf(-qy[i], p.y, d);
                d = fmaf(-qz[i], p.z, d);    // == 0.5*d^2
                mn[i] = fminf(mn[i], d);
            }
        }

        // non-negative float => uint order == float order; poison acts as +inf
#pragma unroll
        for (int i = 0; i < VEC; ++i) {
            const unsigned u = __float_as_uint(fmaxf(mn[i], 0.0f));
            atomicMin(minOut + i * BLOCK + t, u);
        }
    } else {
        // ---------------- edge-length block ----------------
        const int eb = bid - CHAM_BLOCKS;           // 0..383
        const int b  = eb / EPB;
        const int e  = (eb - b * EPB) * BLOCK + t;
        const int i0 = edges[2 * e], i1 = edges[2 * e + 1];
        const float* p0 = pred + ((size_t)b * N + i0) * 3;
        const float* p1 = pred + ((size_t)b * N + i1) * 3;
        const float dx = p0[0] - p1[0];
        const float dy = p0[1] - p1[1];
        const float dz = p0[2] - p1[2];
        float L  = sqrtf(dx * dx + dy * dy + dz * dz);
        float L2 = L * L;
#pragma unroll
        for (int o = 32; o > 0; o >>= 1) {
            L  += __shfl_down(L, o, 64);
            L2 += __shfl_down(L2, o, 64);
        }
        __shared__ float w1[4], w2[4];
        const int wave = t >> 6, lane = t & 63;
        if (lane == 0) { w1[wave] = L; w2[wave] = L2; }
        __syncthreads();
        if (t == 0) {
            float* wsf = (float*)(ws + 2 * B * N);
            wsf[2 * eb]     = w1[0] + w1[1] + w1[2] + w1[3];
            wsf[2 * eb + 1] = w2[0] + w2[1] + w2[2] + w2[3];
        }
    }
}

__global__ __launch_bounds__(1024) void final_kernel(
    const unsigned* __restrict__ ws, float* __restrict__ out) {
    const int t = threadIdx.x;

    // chamfer: 65536 per-query mins -> sqrt -> sum
    float sc = 0.0f;
#pragma unroll 8
    for (int k = 0; k < 64; ++k) {
        const float h = __uint_as_float(ws[t + k * 1024]);
        sc += sqrtf(fmaxf(2.0f * h, 0.0f));
    }
    // edge partials: 384 (sumL, sumL2) pairs
    float s1 = 0.0f, s2 = 0.0f;
    if (t < EDGE_BLOCKS) {
        const float* wsf = (const float*)(ws + 2 * B * N);
        s1 = wsf[2 * t];
        s2 = wsf[2 * t + 1];
    }
#pragma unroll
    for (int o = 32; o > 0; o >>= 1) {
        sc += __shfl_down(sc, o, 64);
        s1 += __shfl_down(s1, o, 64);
        s2 += __shfl_down(s2, o, 64);
    }
    __shared__ float w[3][16];
    const int wave = t >> 6, lane = t & 63;
    if (lane == 0) { w[0][wave] = sc; w[1][wave] = s1; w[2][wave] = s2; }
    __syncthreads();
    if (t == 0) {
        float S = 0.0f, A = 0.0f, C = 0.0f;
#pragma unroll
        for (int i = 0; i < 16; i++) { S += w[0][i]; A += w[1][i]; C += w[2][i]; }
        const float K = (float)(B * E);               // 98304
        const float var = (C - A * A / K) / (K - 1.0f);
        out[0] = S / 32768.0f + 0.1f * var;           // cd + 0.1 * edge_var
    }
}

extern "C" void kernel_launch(void* const* d_in, const int* in_sizes, int n_in,
                              void* d_out, int out_size, void* d_ws, size_t ws_size,
                              hipStream_t stream) {
    const float* pred  = (const float*)d_in[0];
    const float* gt    = (const float*)d_in[1];
    const int*   edges = (const int*)d_in[2];
    float* out = (float*)d_out;
    unsigned* ws = (unsigned*)d_ws;

    fused_kernel<<<CHAM_BLOCKS + EDGE_BLOCKS, BLOCK, 0, stream>>>(pred, gt, edges, ws);
    final_kernel<<<1, 1024, 0, stream>>>(ws, out);
}

// Round 4
// 87.286 us; speedup vs baseline: 1.3684x; 1.0906x over previous
//
#include <hip/hip_runtime.h>
#include <hip/hip_bf16.h>
#include <float.h>

// Problem constants (fixed by setup_inputs)
constexpr int B = 8, N = 4096, M = 4096, E = 12288;
constexpr int CBLOCK = 1024;                 // threads per block
constexpr int CHAM_BLOCKS = 256;             // 2 dir x 8 b x 16 qtiles
constexpr int EDGE_BLOCKS = (B * E) / CBLOCK;// 96
constexpr int SPLIT = 8;                     // ref-sweep split across thread groups
constexpr int RPT = M / SPLIT;               // 512 refs per thread
constexpr int VEC = 2;                       // queries per thread
constexpr int QG = CBLOCK / SPLIT;           // 128 (queries per VEC-slot); 256 q/block

// ws layout (floats): [0..256) chamfer per-block sqrt-sums,
//                     [256..256+192) edge per-block (sumL,sumL2) pairs.
// Every slot written unconditionally -> 0xAA poison harmless, no init kernel.

__global__ __launch_bounds__(CBLOCK) void fused_kernel(
    const float* __restrict__ pred, const float* __restrict__ gt,
    const int* __restrict__ edges, float* __restrict__ ws) {
    const int bid = blockIdx.x;
    const int t = threadIdx.x;

    __shared__ float4 tile[M];               // 64 KB: all refs {x,y,z,0.5|p|^2}
    __shared__ float red[SPLIT * 256];       // 8 KB: per-query partial mins
    __shared__ float wsum[16];

    if (bid < CHAM_BLOCKS) {
        // ---------------- chamfer block ----------------
        const int dir = bid >> 7;            // 0: q=pred/ref=gt, 1: swapped
        const int b   = (bid >> 4) & 7;
        const int qt  = bid & 15;
        const float* __restrict__ q   = dir ? gt   : pred;
        const float* __restrict__ ref = dir ? pred : gt;

        // stage ALL M ref points: thread t loads points 4t..4t+3 (6 coalesced float2)
        {
            const float2* rb = (const float2*)(ref + (size_t)b * M * 3) + 6 * t;
            const float2 r0 = rb[0], r1 = rb[1], r2 = rb[2];
            const float2 r3 = rb[3], r4 = rb[4], r5 = rb[5];
            const float x0=r0.x,y0=r0.y,z0=r1.x, x1=r1.y,y1=r2.x,z1=r2.y;
            const float x2=r3.x,y2=r3.y,z2=r4.x, x3=r4.y,y3=r5.x,z3=r5.y;
            tile[4*t+0] = make_float4(x0,y0,z0, 0.5f*(x0*x0+y0*y0+z0*z0));
            tile[4*t+1] = make_float4(x1,y1,z1, 0.5f*(x1*x1+y1*y1+z1*z1));
            tile[4*t+2] = make_float4(x2,y2,z2, 0.5f*(x2*x2+y2*y2+z2*z2));
            tile[4*t+3] = make_float4(x3,y3,z3, 0.5f*(x3*x3+y3*y3+z3*z3));
        }

        // this thread's VEC queries
        const int qloc = t & (QG - 1);       // 0..127
        const int s    = t >> 7;             // 0..7 -> ref segment
        float qx[VEC], qy[VEC], qz[VEC], h1[VEC];
#pragma unroll
        for (int i = 0; i < VEC; i++) {
            const int n = qt * 256 + qloc + i * QG;
            const float* qp = q + ((size_t)b * N + n) * 3;
            qx[i] = qp[0]; qy[i] = qp[1]; qz[i] = qp[2];
            h1[i] = 0.5f * (qx[i]*qx[i] + qy[i]*qy[i] + qz[i]*qz[i]);
        }
        __syncthreads();

        const float4* tl = tile + s * RPT;
        float mnA[VEC], mnB[VEC];
#pragma unroll
        for (int i = 0; i < VEC; i++) { mnA[i] = FLT_MAX; mnB[i] = FLT_MAX; }

#pragma unroll 2
        for (int m = 0; m < RPT; m += 4) {
            const float4 p0 = tl[m], p1 = tl[m+1], p2 = tl[m+2], p3 = tl[m+3];
#pragma unroll
            for (int i = 0; i < VEC; i++) {
                float d0 = h1[i] + p0.w;
                d0 = fmaf(-qx[i], p0.x, d0); d0 = fmaf(-qy[i], p0.y, d0); d0 = fmaf(-qz[i], p0.z, d0);
                float d1 = h1[i] + p1.w;
                d1 = fmaf(-qx[i], p1.x, d1); d1 = fmaf(-qy[i], p1.y, d1); d1 = fmaf(-qz[i], p1.z, d1);
                float d2 = h1[i] + p2.w;
                d2 = fmaf(-qx[i], p2.x, d2); d2 = fmaf(-qy[i], p2.y, d2); d2 = fmaf(-qz[i], p2.z, d2);
                float d3 = h1[i] + p3.w;
                d3 = fmaf(-qx[i], p3.x, d3); d3 = fmaf(-qy[i], p3.y, d3); d3 = fmaf(-qz[i], p3.z, d3);
                mnA[i] = fminf(mnA[i], fminf(d0, d1));   // two independent chains per query
                mnB[i] = fminf(mnB[i], fminf(d2, d3));
            }
        }

        red[s * 256 + qloc]      = fminf(mnA[0], mnB[0]);
        red[s * 256 + qloc + QG] = fminf(mnA[1], mnB[1]);
        __syncthreads();

        float sv = 0.0f;
        if (t < 256) {
            float m8 = red[t];
#pragma unroll
            for (int k = 1; k < SPLIT; k++) m8 = fminf(m8, red[k * 256 + t]);
            sv = sqrtf(fmaxf(2.0f * m8, 0.0f));          // back to distance
        }
#pragma unroll
        for (int o = 32; o > 0; o >>= 1) sv += __shfl_down(sv, o, 64);
        if ((t & 63) == 0) wsum[t >> 6] = sv;
        __syncthreads();
        if (t == 0) ws[bid] = wsum[0] + wsum[1] + wsum[2] + wsum[3];  // waves 4..15 are zero
    } else {
        // ---------------- edge-length block ----------------
        const int eg = (bid - CHAM_BLOCKS) * CBLOCK + t;  // 0..98303
        const int b  = eg / E;
        const int e  = eg - b * E;
        const int i0 = edges[2 * e], i1 = edges[2 * e + 1];
        const float* p0 = pred + ((size_t)b * N + i0) * 3;
        const float* p1 = pred + ((size_t)b * N + i1) * 3;
        const float dx = p0[0] - p1[0];
        const float dy = p0[1] - p1[1];
        const float dz = p0[2] - p1[2];
        float L  = sqrtf(dx * dx + dy * dy + dz * dz);
        float L2 = L * L;
#pragma unroll
        for (int o = 32; o > 0; o >>= 1) {
            L  += __shfl_down(L, o, 64);
            L2 += __shfl_down(L2, o, 64);
        }
        if ((t & 63) == 0) { red[t >> 6] = L; red[32 + (t >> 6)] = L2; }
        __syncthreads();
        if (t == 0) {
            float a = 0.0f, c = 0.0f;
#pragma unroll
            for (int w = 0; w < 16; w++) { a += red[w]; c += red[32 + w]; }
            const int eb = bid - CHAM_BLOCKS;
            ws[CHAM_BLOCKS + 2 * eb]     = a;
            ws[CHAM_BLOCKS + 2 * eb + 1] = c;
        }
    }
}

__global__ __launch_bounds__(256) void final_kernel(
    const float* __restrict__ ws, float* __restrict__ out) {
    const int t = threadIdx.x;
    float sc = ws[t];                                   // 256 chamfer partials
    float s1 = 0.0f, s2 = 0.0f;
    if (t < EDGE_BLOCKS) {
        s1 = ws[CHAM_BLOCKS + 2 * t];
        s2 = ws[CHAM_BLOCKS + 2 * t + 1];
    }
#pragma unroll
    for (int o = 32; o > 0; o >>= 1) {
        sc += __shfl_down(sc, o, 64);
        s1 += __shfl_down(s1, o, 64);
        s2 += __shfl_down(s2, o, 64);
    }
    __shared__ float w[3][4];
    const int wv = t >> 6, ln = t & 63;
    if (ln == 0) { w[0][wv] = sc; w[1][wv] = s1; w[2][wv] = s2; }
    __syncthreads();
    if (t == 0) {
        float S = 0.0f, A = 0.0f, C = 0.0f;
#pragma unroll
        for (int i = 0; i < 4; i++) { S += w[0][i]; A += w[1][i]; C += w[2][i]; }
        const float K = (float)(B * E);                 // 98304
        const float var = (C - A * A / K) / (K - 1.0f);
        out[0] = S / 32768.0f + 0.1f * var;             // cd + 0.1 * edge_var
    }
}

extern "C" void kernel_launch(void* const* d_in, const int* in_sizes, int n_in,
                              void* d_out, int out_size, void* d_ws, size_t ws_size,
                              hipStream_t stream) {
    const float* pred  = (const float*)d_in[0];
    const float* gt    = (const float*)d_in[1];
    const int*   edges = (const int*)d_in[2];
    float* out = (float*)d_out;
    float* wsf = (float*)d_ws;

    fused_kernel<<<CHAM_BLOCKS + EDGE_BLOCKS, CBLOCK, 0, stream>>>(pred, gt, edges, wsf);
    final_kernel<<<1, 256, 0, stream>>>(wsf, out);
}

// Round 5
// 85.038 us; speedup vs baseline: 1.4045x; 1.0264x over previous
//
#include <hip/hip_runtime.h>
#include <hip/hip_bf16.h>
#include <float.h>

// Problem constants (fixed by setup_inputs)
constexpr int B = 8, N = 4096, M = 4096, E = 12288;
constexpr int CBLOCK = 1024;                  // threads per block
constexpr int EDGE_BLOCKS = (B * E) / CBLOCK; // 96 (placed FIRST in grid)
constexpr int CHAM_BLOCKS = 2 * B * (N / 256);// 256 (2 dir x 8 b x 16 qtiles)
constexpr int SPLIT = 32;                     // ref-sweep split across thread groups
constexpr int RPT = M / SPLIT;                // 128 refs per thread
constexpr int VEC = 8;                        // register queries per thread
constexpr int QB = 256;                       // queries per block (CBLOCK*VEC/SPLIT)

// ws layout (floats): [0..192) edge per-block (sumL,sumL2) pairs,
//                     [192..192+256) chamfer per-block sqrt-sums.
// Every slot written unconditionally -> 0xAA poison harmless, no init kernel.

__global__ __launch_bounds__(CBLOCK) void fused_kernel(
    const float* __restrict__ pred, const float* __restrict__ gt,
    const int* __restrict__ edges, float* __restrict__ ws) {
    const int bid = blockIdx.x;
    const int t = threadIdx.x;

    __shared__ float4 tile[M];                // 64 KB: refs {x,y,z,0.5|p|^2}
    __shared__ float wsum[16];
    float* red = (float*)tile;                // aliased: tile dead before red used

    if (bid >= EDGE_BLOCKS) {
        // ---------------- chamfer block ----------------
        const int cb  = bid - EDGE_BLOCKS;    // 0..255
        const int dir = cb >> 7;              // 0: q=pred/ref=gt, 1: swapped
        const int b   = (cb >> 4) & 7;
        const int qt  = cb & 15;
        const float* __restrict__ q   = dir ? gt   : pred;
        const float* __restrict__ ref = dir ? pred : gt;

        // stage ALL M ref points: thread t loads points 4t..4t+3 (6 coalesced float2)
        {
            const float2* rb = (const float2*)(ref + (size_t)b * M * 3) + 6 * t;
            const float2 r0 = rb[0], r1 = rb[1], r2 = rb[2];
            const float2 r3 = rb[3], r4 = rb[4], r5 = rb[5];
            const float x0=r0.x,y0=r0.y,z0=r1.x, x1=r1.y,y1=r2.x,z1=r2.y;
            const float x2=r3.x,y2=r3.y,z2=r4.x, x3=r4.y,y3=r5.x,z3=r5.y;
            tile[4*t+0] = make_float4(x0,y0,z0, 0.5f*(x0*x0+y0*y0+z0*z0));
            tile[4*t+1] = make_float4(x1,y1,z1, 0.5f*(x1*x1+y1*y1+z1*z1));
            tile[4*t+2] = make_float4(x2,y2,z2, 0.5f*(x2*x2+y2*y2+z2*z2));
            tile[4*t+3] = make_float4(x3,y3,z3, 0.5f*(x3*x3+y3*y3+z3*z3));
        }

        // this thread's VEC=8 register queries
        const int qloc = t & 31;              // 0..31
        const int s    = t >> 5;              // 0..31 -> ref segment
        float qx[VEC], qy[VEC], qz[VEC], h1[VEC];
#pragma unroll
        for (int i = 0; i < VEC; i++) {
            const int n = qt * QB + qloc + i * 32;
            const float* qp = q + ((size_t)b * N + n) * 3;
            qx[i] = qp[0]; qy[i] = qp[1]; qz[i] = qp[2];
            h1[i] = 0.5f * (qx[i]*qx[i] + qy[i]*qy[i] + qz[i]*qz[i]);
        }
        __syncthreads();

        const float4* tl = tile + s * RPT;
        float mn[VEC];
#pragma unroll
        for (int i = 0; i < VEC; i++) mn[i] = FLT_MAX;

        // 2-point register prefetch; 8 independent min-chains per point pair
        float4 pA = tl[0], pB = tl[1];
#pragma unroll 2
        for (int m = 0; m < RPT - 2; m += 2) {
            const float4 nA = tl[m + 2], nB = tl[m + 3];
#pragma unroll
            for (int i = 0; i < VEC; i++) {
                float d0 = fmaf(-qx[i], pA.x, h1[i] + pA.w);
                d0 = fmaf(-qy[i], pA.y, d0);
                d0 = fmaf(-qz[i], pA.z, d0);
                float d1 = fmaf(-qx[i], pB.x, h1[i] + pB.w);
                d1 = fmaf(-qy[i], pB.y, d1);
                d1 = fmaf(-qz[i], pB.z, d1);
                mn[i] = fminf(mn[i], fminf(d0, d1));   // v_min3 fusion hoped
            }
            pA = nA; pB = nB;
        }
#pragma unroll
        for (int i = 0; i < VEC; i++) {
            float d0 = fmaf(-qx[i], pA.x, h1[i] + pA.w);
            d0 = fmaf(-qy[i], pA.y, d0);
            d0 = fmaf(-qz[i], pA.z, d0);
            float d1 = fmaf(-qx[i], pB.x, h1[i] + pB.w);
            d1 = fmaf(-qy[i], pB.y, d1);
            d1 = fmaf(-qz[i], pB.z, d1);
            mn[i] = fminf(mn[i], fminf(d0, d1));
        }
        __syncthreads();                      // tile dead; red alias live

        // combine segment pairs in-register, then 16 wave-partials per query
        const int wv = t >> 6;                // 0..15
#pragma unroll
        for (int i = 0; i < VEC; i++)
            mn[i] = fminf(mn[i], __shfl_xor(mn[i], 32, 64));
        if ((t & 32) == 0) {
#pragma unroll
            for (int i = 0; i < VEC; i++)
                red[(qloc + i * 32) + 256 * wv] = mn[i];   // bank-conflict-free
        }
        __syncthreads();

        float sv = 0.0f;
        if (t < QB) {
            float m = red[t];
#pragma unroll
            for (int w = 1; w < 16; w++) m = fminf(m, red[t + 256 * w]);
            sv = sqrtf(fmaxf(2.0f * m, 0.0f));            // back to distance
        }
#pragma unroll
        for (int o = 32; o > 0; o >>= 1) sv += __shfl_down(sv, o, 64);
        if ((t & 63) == 0) wsum[wv] = sv;
        __syncthreads();
        if (t == 0)
            ws[2 * EDGE_BLOCKS + cb] = wsum[0] + wsum[1] + wsum[2] + wsum[3];
    } else {
        // ---------------- edge-length block ----------------
        const int eg = bid * CBLOCK + t;      // 0..98303
        const int b  = eg / E;
        const int e  = eg - b * E;
        const int i0 = edges[2 * e], i1 = edges[2 * e + 1];
        const float* p0 = pred + ((size_t)b * N + i0) * 3;
        const float* p1 = pred + ((size_t)b * N + i1) * 3;
        const float dx = p0[0] - p1[0];
        const float dy = p0[1] - p1[1];
        const float dz = p0[2] - p1[2];
        float L  = sqrtf(dx * dx + dy * dy + dz * dz);
        float L2 = L * L;
#pragma unroll
        for (int o = 32; o > 0; o >>= 1) {
            L  += __shfl_down(L, o, 64);
            L2 += __shfl_down(L2, o, 64);
        }
        if ((t & 63) == 0) { red[t >> 6] = L; red[32 + (t >> 6)] = L2; }
        __syncthreads();
        if (t == 0) {
            float a = 0.0f, c = 0.0f;
#pragma unroll
            for (int w = 0; w < 16; w++) { a += red[w]; c += red[32 + w]; }
            ws[2 * bid]     = a;
            ws[2 * bid + 1] = c;
        }
    }
}

__global__ __launch_bounds__(256) void final_kernel(
    const float* __restrict__ ws, float* __restrict__ out) {
    const int t = threadIdx.x;
    float sc = ws[2 * EDGE_BLOCKS + t];       // 256 chamfer partials
    float s1 = 0.0f, s2 = 0.0f;
    if (t < EDGE_BLOCKS) {
        s1 = ws[2 * t];
        s2 = ws[2 * t + 1];
    }
#pragma unroll
    for (int o = 32; o > 0; o >>= 1) {
        sc += __shfl_down(sc, o, 64);
        s1 += __shfl_down(s1, o, 64);
        s2 += __shfl_down(s2, o, 64);
    }
    __shared__ float w[3][4];
    const int wv = t >> 6, ln = t & 63;
    if (ln == 0) { w[0][wv] = sc; w[1][wv] = s1; w[2][wv] = s2; }
    __syncthreads();
    if (t == 0) {
        float S = 0.0f, A = 0.0f, C = 0.0f;
#pragma unroll
        for (int i = 0; i < 4; i++) { S += w[0][i]; A += w[1][i]; C += w[2][i]; }
        const float K = (float)(B * E);       // 98304
        const float var = (C - A * A / K) / (K - 1.0f);
        out[0] = S / 32768.0f + 0.1f * var;   // cd + 0.1 * edge_var
    }
}

extern "C" void kernel_launch(void* const* d_in, const int* in_sizes, int n_in,
                              void* d_out, int out_size, void* d_ws, size_t ws_size,
                              hipStream_t stream) {
    const float* pred  = (const float*)d_in[0];
    const float* gt    = (const float*)d_in[1];
    const int*   edges = (const int*)d_in[2];
    float* out = (float*)d_out;
    float* wsf = (float*)d_ws;

    fused_kernel<<<EDGE_BLOCKS + CHAM_BLOCKS, CBLOCK, 0, stream>>>(pred, gt, edges, wsf);
    final_kernel<<<1, 256, 0, stream>>>(wsf, out);
}

// Round 6
// 83.919 us; speedup vs baseline: 1.4232x; 1.0133x over previous
//
#include <hip/hip_runtime.h>
#include <hip/hip_bf16.h>
#include <float.h>

// Problem constants (fixed by setup_inputs)
constexpr int B = 8, N = 4096, M = 4096, E = 12288;
constexpr int CBLOCK = 1024;                  // threads per block
constexpr int EDGE_BLOCKS = (B * E) / CBLOCK; // 96 (first in grid; short-lived)
constexpr int CHAM_BLOCKS = 2 * B * (N / 256);// 256 (2 dir x 8 b x 16 qtiles)
constexpr int SPLIT = 64;                     // ref-sweep split across thread groups
constexpr int RPT = M / SPLIT;                // 64 refs per thread
constexpr int VEC = 16;                       // register queries per thread
constexpr int QB = 256;                       // queries per block

// ws layout (floats): [0..192) edge per-block (sumL,sumL2) pairs,
//                     [192..192+256) chamfer per-block sqrt-sums.
// Every slot written unconditionally -> 0xAA poison harmless, no init kernel.

__global__ __launch_bounds__(CBLOCK) void fused_kernel(
    const float* __restrict__ pred, const float* __restrict__ gt,
    const int* __restrict__ edges, float* __restrict__ ws) {
    const int bid = blockIdx.x;
    const int t = threadIdx.x;

    __shared__ float4 tile[M];                // 64 KB: refs {x,y,z,0.5|p|^2}
    __shared__ float wsum[16];
    float* red = (float*)tile;                // aliased [SPLIT][QB]: tile dead first

    if (bid >= EDGE_BLOCKS) {
        // ---------------- chamfer block ----------------
        const int cb  = bid - EDGE_BLOCKS;    // 0..255
        const int dir = cb >> 7;              // 0: q=pred/ref=gt, 1: swapped
        const int b   = (cb >> 4) & 7;
        const int qt  = cb & 15;
        const float* __restrict__ q   = dir ? gt   : pred;
        const float* __restrict__ ref = dir ? pred : gt;

        // stage ALL M ref points: thread t loads points 4t..4t+3 (6 coalesced float2)
        {
            const float2* rb = (const float2*)(ref + (size_t)b * M * 3) + 6 * t;
            const float2 r0 = rb[0], r1 = rb[1], r2 = rb[2];
            const float2 r3 = rb[3], r4 = rb[4], r5 = rb[5];
            const float x0=r0.x,y0=r0.y,z0=r1.x, x1=r1.y,y1=r2.x,z1=r2.y;
            const float x2=r3.x,y2=r3.y,z2=r4.x, x3=r4.y,y3=r5.x,z3=r5.y;
            tile[4*t+0] = make_float4(x0,y0,z0, 0.5f*(x0*x0+y0*y0+z0*z0));
            tile[4*t+1] = make_float4(x1,y1,z1, 0.5f*(x1*x1+y1*y1+z1*z1));
            tile[4*t+2] = make_float4(x2,y2,z2, 0.5f*(x2*x2+y2*y2+z2*z2));
            tile[4*t+3] = make_float4(x3,y3,z3, 0.5f*(x3*x3+y3*y3+z3*z3));
        }

        // this thread's VEC=16 register queries (|q|^2 handled in the tail)
        const int qloc = t & 15;              // 0..15
        const int s    = t >> 4;              // 0..63 -> ref segment
        float qx[VEC], qy[VEC], qz[VEC];
#pragma unroll
        for (int i = 0; i < VEC; i++) {
            const int n = qt * QB + qloc + i * 16;
            const float* qp = q + ((size_t)b * N + n) * 3;
            qx[i] = qp[0]; qy[i] = qp[1]; qz[i] = qp[2];
        }
        __syncthreads();

        const float4* tl = tile + s * RPT;
        float mn[VEC];
#pragma unroll
        for (int i = 0; i < VEC; i++) mn[i] = FLT_MAX;

        // accumulate min of (0.5|p|^2 - q.p): 3 FMA per point per query
        float4 pA = tl[0], pB = tl[1];
#pragma unroll 2
        for (int m = 0; m < RPT - 2; m += 2) {
            const float4 nA = tl[m + 2], nB = tl[m + 3];
#pragma unroll
            for (int i = 0; i < VEC; i++) {
                float d0 = fmaf(-qz[i], pA.z, pA.w);
                d0 = fmaf(-qy[i], pA.y, d0);
                d0 = fmaf(-qx[i], pA.x, d0);
                float d1 = fmaf(-qz[i], pB.z, pB.w);
                d1 = fmaf(-qy[i], pB.y, d1);
                d1 = fmaf(-qx[i], pB.x, d1);
                mn[i] = fminf(mn[i], fminf(d0, d1));   // -> v_min3_f32
            }
            pA = nA; pB = nB;
        }
#pragma unroll
        for (int i = 0; i < VEC; i++) {
            float d0 = fmaf(-qz[i], pA.z, pA.w);
            d0 = fmaf(-qy[i], pA.y, d0);
            d0 = fmaf(-qx[i], pA.x, d0);
            float d1 = fmaf(-qz[i], pB.z, pB.w);
            d1 = fmaf(-qy[i], pB.y, d1);
            d1 = fmaf(-qx[i], pB.x, d1);
            mn[i] = fminf(mn[i], fminf(d0, d1));
        }
        __syncthreads();                      // tile dead; red alias live

        // seg-major partials: red[s][q]
#pragma unroll
        for (int i = 0; i < VEC; i++)
            red[s * QB + qloc + i * 16] = mn[i];
        __syncthreads();

        float sv = 0.0f;
        if (t < QB) {
            float m = red[t];                 // conflict-free column reads
#pragma unroll 8
            for (int k = 1; k < SPLIT; k++) m = fminf(m, red[k * QB + t]);
            // add back |q|^2: d = sqrt(max(2*m + |q|^2, 0))
            const float* qp = q + ((size_t)b * N + qt * QB + t) * 3;
            const float sq = qp[0]*qp[0] + qp[1]*qp[1] + qp[2]*qp[2];
            sv = sqrtf(fmaxf(2.0f * m + sq, 0.0f));
        }
#pragma unroll
        for (int o = 32; o > 0; o >>= 1) sv += __shfl_down(sv, o, 64);
        if ((t & 63) == 0) wsum[t >> 6] = sv;
        __syncthreads();
        if (t == 0)
            ws[2 * EDGE_BLOCKS + cb] = wsum[0] + wsum[1] + wsum[2] + wsum[3];
    } else {
        // ---------------- edge-length block ----------------
        const int eg = bid * CBLOCK + t;      // 0..98303
        const int b  = eg / E;
        const int e  = eg - b * E;
        const int i0 = edges[2 * e], i1 = edges[2 * e + 1];
        const float* p0 = pred + ((size_t)b * N + i0) * 3;
        const float* p1 = pred + ((size_t)b * N + i1) * 3;
        const float dx = p0[0] - p1[0];
        const float dy = p0[1] - p1[1];
        const float dz = p0[2] - p1[2];
        float L  = sqrtf(dx * dx + dy * dy + dz * dz);
        float L2 = L * L;
#pragma unroll
        for (int o = 32; o > 0; o >>= 1) {
            L  += __shfl_down(L, o, 64);
            L2 += __shfl_down(L2, o, 64);
        }
        if ((t & 63) == 0) { red[t >> 6] = L; red[32 + (t >> 6)] = L2; }
        __syncthreads();
        if (t == 0) {
            float a = 0.0f, c = 0.0f;
#pragma unroll
            for (int w = 0; w < 16; w++) { a += red[w]; c += red[32 + w]; }
            ws[2 * bid]     = a;
            ws[2 * bid + 1] = c;
        }
    }
}

__global__ __launch_bounds__(256) void final_kernel(
    const float* __restrict__ ws, float* __restrict__ out) {
    const int t = threadIdx.x;
    float sc = ws[2 * EDGE_BLOCKS + t];       // 256 chamfer partials
    float s1 = 0.0f, s2 = 0.0f;
    if (t < EDGE_BLOCKS) {
        s1 = ws[2 * t];
        s2 = ws[2 * t + 1];
    }
#pragma unroll
    for (int o = 32; o > 0; o >>= 1) {
        sc += __shfl_down(sc, o, 64);
        s1 += __shfl_down(s1, o, 64);
        s2 += __shfl_down(s2, o, 64);
    }
    __shared__ float w[3][4];
    const int wv = t >> 6, ln = t & 63;
    if (ln == 0) { w[0][wv] = sc; w[1][wv] = s1; w[2][wv] = s2; }
    __syncthreads();
    if (t == 0) {
        float S = 0.0f, A = 0.0f, C = 0.0f;
#pragma unroll
        for (int i = 0; i < 4; i++) { S += w[0][i]; A += w[1][i]; C += w[2][i]; }
        const float K = (float)(B * E);       // 98304
        const float var = (C - A * A / K) / (K - 1.0f);
        out[0] = S / 32768.0f + 0.1f * var;   // cd + 0.1 * edge_var
    }
}

extern "C" void kernel_launch(void* const* d_in, const int* in_sizes, int n_in,
                              void* d_out, int out_size, void* d_ws, size_t ws_size,
                              hipStream_t stream) {
    const float* pred  = (const float*)d_in[0];
    const float* gt    = (const float*)d_in[1];
    const int*   edges = (const int*)d_in[2];
    float* out = (float*)d_out;
    float* wsf = (float*)d_ws;

    fused_kernel<<<EDGE_BLOCKS + CHAM_BLOCKS, CBLOCK, 0, stream>>>(pred, gt, edges, wsf);
    final_kernel<<<1, 256, 0, stream>>>(wsf, out);
}